// Round 6
// baseline (147.788 us; speedup 1.0000x reference)
//
#include <hip/hip_runtime.h>

// Locally-connected conv (BioConvolution): per-patch GEMM
//   Z[n,p,o] = sum_k X_patch[n,p,k] * F[p,k,o],  K=512, N=FOUT=32, P=1024
//   A = relu(Z + bias)
// NO LDS STAGING: MFMA fragments are loaded straight from global into the
// lanes that need them (A: 2x dwordx4/lane; B: 8x dword/lane, 4 full
// lines/instr). Block = 256 thr = 4 waves = one patch; wave w owns K-quarter
// w (= patch row w; every input byte read exactly once per block), computes
// all four 16x16 tiles, 16 KiB LDS cross-wave reduce at the end.
// 2-deep register software pipeline, sched_barrier(0) pins load issue.
// grid=1024 -> exactly 4 blocks/CU, all resident from t=0.

typedef __attribute__((ext_vector_type(4))) float f32x4;
typedef __attribute__((ext_vector_type(8))) short s16x8;

#define HWC (128 * 128 * 32)   // per-batch X stride (floats)
#define WC  (128 * 32)         // per-row X stride (floats)

__device__ __forceinline__ short f2bf(float f) {
    // round-to-nearest-even fp32 -> bf16
    unsigned u = __builtin_bit_cast(unsigned, f);
    u += 0x7fffu + ((u >> 16) & 1u);
    return (short)(u >> 16);
}
__device__ __forceinline__ s16x8 pack8(const f32x4 lo, const f32x4 hi) {
    s16x8 r;
    r[0] = f2bf(lo[0]); r[1] = f2bf(lo[1]); r[2] = f2bf(lo[2]); r[3] = f2bf(lo[3]);
    r[4] = f2bf(hi[0]); r[5] = f2bf(hi[1]); r[6] = f2bf(hi[2]); r[7] = f2bf(hi[3]);
    return r;
}
__device__ __forceinline__ s16x8 pack8f(const float* b) {
    s16x8 r;
    #pragma unroll
    for (int j = 0; j < 8; ++j) r[j] = f2bf(b[j]);
    return r;
}

__launch_bounds__(256, 4)
__global__ void lcconv_kernel(const float* __restrict__ X,
                              const float* __restrict__ F,
                              const float* __restrict__ bias,
                              float* __restrict__ out) {
    __shared__ f32x4 red[4][4][64];   // [src wave][tile][lane] = 16 KiB

    const int p    = blockIdx.x;
    const int pr   = p >> 5;
    const int pc   = p & 31;
    const int tid  = threadIdx.x;
    const int lane = tid & 63;
    const int w    = tid >> 6;        // wave = K-quarter = patch row i
    const int col  = lane & 15;       // n for A-frag, o for B-frag
    const int g    = lane >> 4;       // k sub-group within a 32-step

    // A: lane needs X[n = nh*16+col][patch row w][k_local = ks*32 + g*8 + 0..7]
    const float* A0p = X + col * HWC + (pr * 4 + w) * WC + pc * 128 + g * 8;
    const float* A1p = A0p + 16 * HWC;                   // n-half 1
    // B: lane needs F[p][k = w*128 + ks*32 + g*8 + j][o = oh*16 + col]
    const float* Bp  = F + p * (512 * 32) + (w * 128 + g * 8) * 32 + col;

    f32x4 aA[2][2], aB[2][2];         // [nh][lo/hi 4-float group]
    float bA[2][8], bB[2][8];         // [oh][j]

    auto load = [&](int ks, f32x4 (&a)[2][2], float (&b)[2][8]) {
        const float* a0 = A0p + ks * 32;
        const float* a1 = A1p + ks * 32;
        a[0][0] = *(const f32x4*)(a0);  a[0][1] = *(const f32x4*)(a0 + 4);
        a[1][0] = *(const f32x4*)(a1);  a[1][1] = *(const f32x4*)(a1 + 4);
        const float* bp = Bp + ks * 1024;
        #pragma unroll
        for (int j = 0; j < 8; ++j) {
            b[0][j] = bp[j * 32];
            b[1][j] = bp[j * 32 + 16];
        }
    };

    f32x4 acc00{0,0,0,0}, acc01{0,0,0,0}, acc10{0,0,0,0}, acc11{0,0,0,0};
    auto compute = [&](const f32x4 (&a)[2][2], const float (&b)[2][8]) {
        s16x8 A0 = pack8(a[0][0], a[0][1]);
        s16x8 A1 = pack8(a[1][0], a[1][1]);
        s16x8 B0 = pack8f(b[0]);
        s16x8 B1 = pack8f(b[1]);
        acc00 = __builtin_amdgcn_mfma_f32_16x16x32_bf16(A0, B0, acc00, 0, 0, 0);
        acc01 = __builtin_amdgcn_mfma_f32_16x16x32_bf16(A0, B1, acc01, 0, 0, 0);
        acc10 = __builtin_amdgcn_mfma_f32_16x16x32_bf16(A1, B0, acc10, 0, 0, 0);
        acc11 = __builtin_amdgcn_mfma_f32_16x16x32_bf16(A1, B1, acc11, 0, 0, 0);
    };

    // 2-deep pipeline over the 4 k-steps of this wave's K-quarter.
    load(0, aA, bA);
    load(1, aB, bB);
    __builtin_amdgcn_sched_barrier(0);   // loads may not sink below here
    compute(aA, bA);
    load(2, aA, bA);
    __builtin_amdgcn_sched_barrier(0);
    compute(aB, bB);
    load(3, aB, bB);
    __builtin_amdgcn_sched_barrier(0);
    compute(aA, bA);
    compute(aB, bB);

    // ---- cross-wave K reduction (tiles: t = nh*2 + oh) ----
    red[w][0][lane] = acc00;
    red[w][1][lane] = acc01;
    red[w][2][lane] = acc10;
    red[w][3][lane] = acc11;
    __syncthreads();

    const int nh = w >> 1, oh = w & 1;   // wave w finalizes tile w
    f32x4 s  = red[0][w][lane];
    f32x4 t1 = red[1][w][lane];
    f32x4 t2 = red[2][w][lane];
    f32x4 t3 = red[3][w][lane];
    s += t1; s += t2; s += t3;

    // C/D layout: col o = lane&15, row n = (lane>>4)*4 + reg
    const int o_g = oh * 16 + col;
    const float bv = bias[o_g];
    #pragma unroll
    for (int r = 0; r < 4; ++r) {
        int n_g = nh * 16 + g * 4 + r;
        float v = s[r] + bv;
        v = v > 0.f ? v : 0.f;
        out[n_g * (1024 * 32) + p * 32 + o_g] = v;
    }
}

extern "C" void kernel_launch(void* const* d_in, const int* in_sizes, int n_in,
                              void* d_out, int out_size, void* d_ws, size_t ws_size,
                              hipStream_t stream) {
    const float* X    = (const float*)d_in[0];
    const float* F    = (const float*)d_in[1];
    const float* bias = (const float*)d_in[2];
    float* out        = (float*)d_out;
    lcconv_kernel<<<dim3(1024), dim3(256), 0, stream>>>(X, F, bias, out);
}